// Round 4
// baseline (1097.532 us; speedup 1.0000x reference)
//
#include <hip/hip_runtime.h>
#include <hip/hip_fp16.h>

#define NF 128    // feature dim, fixed by the problem
#define KC 64     // edge chunks
#define NPART 4   // node partitions (N/4 ints must fit LDS: 12500*4B = 50KB)
#define NPMAX 12544

typedef _Float16 half8  __attribute__((ext_vector_type(8)));
typedef _Float16 half4v __attribute__((ext_vector_type(4)));
typedef float    floatx4 __attribute__((ext_vector_type(4)));

// ---------------- count2: LDS histogram per (chunk, partition) -------------------
__global__ __launch_bounds__(512) void count2_k(
    const int* __restrict__ dst, unsigned char* __restrict__ pcnt,
    int E, int N, int Ec)
{
    __shared__ int lcnt[NPMAX];
    const int p = blockIdx.x & 3, c = blockIdx.x >> 2;
    const int Np = (N + 3) >> 2;
    const int lo = p * Np, hi = min(lo + Np, N);
    const int sz = hi - lo;
    for (int i = threadIdx.x; i < sz; i += 512) lcnt[i] = 0;
    __syncthreads();

    const int e0 = c * Ec, e1 = min(e0 + Ec, E);
    for (int e = e0 + (int)threadIdx.x * 4; e + 3 < e1; e += 512 * 4) {
        int4 d = *(const int4*)(dst + e);
        if (d.x >= lo && d.x < hi) atomicAdd(&lcnt[d.x - lo], 1);
        if (d.y >= lo && d.y < hi) atomicAdd(&lcnt[d.y - lo], 1);
        if (d.z >= lo && d.z < hi) atomicAdd(&lcnt[d.z - lo], 1);
        if (d.w >= lo && d.w < hi) atomicAdd(&lcnt[d.w - lo], 1);
    }
    int rem0 = e0 + ((e1 - e0) & ~3);
    for (int e = rem0 + (int)threadIdx.x; e < e1; e += 512) {
        int d = dst[e];
        if (d >= lo && d < hi) atomicAdd(&lcnt[d - lo], 1);
    }
    __syncthreads();
    for (int i = threadIdx.x; i < sz; i += 512)
        pcnt[(size_t)c * N + lo + i] = (unsigned char)lcnt[i];
}

// ---------------- pscan2 (+fused W-transpose) ------------------------------------
__global__ __launch_bounds__(256) void pscan2_k(
    unsigned char* __restrict__ pcnt, float* __restrict__ dinv,
    int* __restrict__ rowptr, int* __restrict__ blocksum, int n, int N, int nb,
    const float* __restrict__ W1, const float* __restrict__ W2,
    __half* __restrict__ WT1, __half* __restrict__ WT2)
{
    if ((int)blockIdx.x >= nb) {
        int idx = ((int)blockIdx.x - nb) * 256 + threadIdx.x;   // 0..32767
        const float* W = (idx < 16384) ? W1 : W2;
        __half* WT     = (idx < 16384) ? WT1 : WT2;
        int j = idx & 16383;
        int nn = j & 127, k = j >> 7;
        WT[nn * NF + k] = __float2half(W[k * NF + nn]);
        return;
    }
    __shared__ int sm[256];
    int tid = threadIdx.x;
    int bin = blockIdx.x * 256 + tid;
    int total = 0;
    if (bin < n) {
        #pragma unroll 4
        for (int c = 0; c < KC; c++) {
            size_t o = (size_t)c * N + bin;
            int v = pcnt[o];
            pcnt[o] = (unsigned char)total;   // exclusive chunk prefix (coff)
            total += v;
        }
        dinv[bin] = rsqrtf((float)total + 1.0f);  // +1 = self-loop
    }
    sm[tid] = total;
    __syncthreads();
    #pragma unroll
    for (int d = 1; d < 256; d <<= 1) {
        int t = (tid >= d) ? sm[tid - d] : 0;
        __syncthreads();
        sm[tid] += t;
        __syncthreads();
    }
    if (bin < n) rowptr[bin] = sm[tid] - total;    // local exclusive prefix
    if (tid == 255) blocksum[blockIdx.x] = sm[255];
}

// ---------------- MFMA GEMM body (512 threads, 128 rows/block) -------------------
template<bool F32IN>
__device__ __forceinline__ void gemm_body512(
    const void* __restrict__ Xv, const __half* __restrict__ WT,
    const float* __restrict__ dinv, __half* __restrict__ out, int M, int bid,
    __half (*wlds)[136])
{
    const int tid = threadIdx.x;
    {   // stage WT (128x128 halves): 4 threads/row, 32 halves each
        int r = tid >> 2;
        int c0 = (tid & 3) * 32;
        const half8* s = (const half8*)(WT + (size_t)r * NF + c0);
        half8* d = (half8*)&wlds[r][c0];
        #pragma unroll
        for (int j = 0; j < 4; j++) d[j] = s[j];
    }
    __syncthreads();

    const int wave = tid >> 6, lane = tid & 63;
    const int quad = lane >> 4, l15 = lane & 15;
    const int rowA = bid * 128 + wave * 16 + l15;
    const int rowc = (rowA < M) ? rowA : (M - 1);

    half8 afr[4];
    if (F32IN) {
        const float* X = (const float*)Xv;
        #pragma unroll
        for (int kc = 0; kc < 4; kc++) {
            const floatx4* p = (const floatx4*)(X + (size_t)rowc * NF + kc * 32 + quad * 8);
            floatx4 u = p[0], v = p[1];
            half8 a;
            a[0] = (_Float16)u[0]; a[1] = (_Float16)u[1];
            a[2] = (_Float16)u[2]; a[3] = (_Float16)u[3];
            a[4] = (_Float16)v[0]; a[5] = (_Float16)v[1];
            a[6] = (_Float16)v[2]; a[7] = (_Float16)v[3];
            afr[kc] = a;
        }
    } else {
        const __half* X = (const __half*)Xv;
        #pragma unroll
        for (int kc = 0; kc < 4; kc++)
            afr[kc] = *(const half8*)(X + (size_t)rowc * NF + kc * 32 + quad * 8);
    }

    floatx4 acc[8];
    #pragma unroll
    for (int ct = 0; ct < 8; ct++) { floatx4 z = {0.f, 0.f, 0.f, 0.f}; acc[ct] = z; }

    #pragma unroll
    for (int kc = 0; kc < 4; kc++) {
        #pragma unroll
        for (int ct = 0; ct < 8; ct++) {
            half8 b = *(const half8*)&wlds[ct * 16 + l15][kc * 32 + quad * 8];
            acc[ct] = __builtin_amdgcn_mfma_f32_16x16x32_f16(afr[kc], b, acc[ct], 0, 0, 0);
        }
    }

    const int orow0 = bid * 128 + wave * 16 + quad * 4;
    #pragma unroll
    for (int r = 0; r < 4; r++) {
        int orow = orow0 + r;
        if (orow < M) {
            float s = dinv[orow];
            #pragma unroll
            for (int ct = 0; ct < 8; ct++)
                out[(size_t)orow * NF + ct * 16 + l15] = __float2half(acc[ct][r] * s);
        }
    }
}

// ---------------- mid_k: fused gemm1 + fill (+add_off) ---------------------------
__global__ __launch_bounds__(512) void mid_k(
    const int* __restrict__ src, const int* __restrict__ dst,
    const int* __restrict__ rowptr, const unsigned char* __restrict__ coff,
    const int* __restrict__ blocksum, int* __restrict__ rowptr2,
    int* __restrict__ csr, int E, int N, int Ec, int nb,
    const float* __restrict__ X, const __half* __restrict__ WT,
    const float* __restrict__ dinv, __half* __restrict__ H, int GB2)
{
    __shared__ __align__(16) char smem[NPMAX * 4 + 1024];   // 51.2KB union
    const int tid = threadIdx.x;
    if ((int)blockIdx.x < GB2) {
        gemm_body512<true>(X, WT, dinv, H, N, blockIdx.x, (__half(*)[136])smem);
        return;
    }
    int* lcur = (int*)smem;
    int* pref = (int*)(smem + NPMAX * 4);

    const int b = blockIdx.x - GB2;
    const int p = b & 3, c = b >> 2;
    const int Np = (N + 3) >> 2;
    const int lo = p * Np, hi = min(lo + Np, N);
    const int sz = hi - lo;

    // exclusive prefix of blocksum[0..nb) in pref
    int v = (tid < nb) ? blocksum[tid] : 0;
    if (tid < 256) pref[tid] = v;
    __syncthreads();
    #pragma unroll
    for (int d = 1; d < 256; d <<= 1) {
        int t = (tid < 256 && tid >= d) ? pref[tid - d] : 0;
        __syncthreads();
        if (tid < 256) pref[tid] += t;
        __syncthreads();
    }
    if (tid < 256) pref[tid] -= v;
    __syncthreads();

    for (int i = tid; i < sz; i += 512) {
        int bin = lo + i;
        int r = rowptr[bin] + pref[bin >> 8] + (int)coff[(size_t)c * N + bin];
        lcur[i] = r;
        if (c == 0) rowptr2[bin] = r;
    }
    if (c == 0 && p == 0 && tid == 0) rowptr2[N] = E;
    __syncthreads();

    const int e0 = c * Ec, e1 = min(e0 + Ec, E);
    for (int e = e0 + tid * 4; e + 3 < e1; e += 512 * 4) {
        int4 d = *(const int4*)(dst + e);
        int4 s = *(const int4*)(src + e);
        if (d.x >= lo && d.x < hi) csr[atomicAdd(&lcur[d.x - lo], 1)] = s.x;
        if (d.y >= lo && d.y < hi) csr[atomicAdd(&lcur[d.y - lo], 1)] = s.y;
        if (d.z >= lo && d.z < hi) csr[atomicAdd(&lcur[d.z - lo], 1)] = s.z;
        if (d.w >= lo && d.w < hi) csr[atomicAdd(&lcur[d.w - lo], 1)] = s.w;
    }
    int rem0 = e0 + ((e1 - e0) & ~3);
    for (int e = rem0 + tid; e < e1; e += 512) {
        int d = dst[e];
        if (d >= lo && d < hi) csr[atomicAdd(&lcur[d - lo], 1)] = src[e];
    }
}

// ---------------- pipelined gather: 8 nodes/wave, depth-3 round pipeline ---------
// All idx preloaded -> loads of round s+3 are independent of accum(round s);
// the only cross-round dependency in R3 was v-register reuse. Triple-buffer
// (va/vb/vc) so each round's accum runs with 16+ loads of later rounds in
// flight: 3 rounds per memory latency instead of 1.
__device__ __forceinline__ void g8_issue(
    const half4v* __restrict__ hs4, const int idx[8], const int cc[8],
    int e2, int eg, int fl, half4v buf[8])
{
    int si[8];
    #pragma unroll
    for (int k = 0; k < 8; k++) {
        int ec = min(e2 + eg, cc[k] - 1);
        ec = (ec < 0) ? 0 : ec;
        si[k] = __shfl(idx[k], ec, 64);
    }
    #pragma unroll
    for (int k = 0; k < 8; k++)
        buf[k] = hs4[(size_t)si[k] * 32 + fl];
}

__device__ __forceinline__ void g8_accum(
    const half4v buf[8], const int cc[8], int e2, int eg, floatx4 acc[8])
{
    #pragma unroll
    for (int k = 0; k < 8; k++) {
        if (e2 + eg < cc[k]) {
            acc[k][0] += (float)buf[k][0]; acc[k][1] += (float)buf[k][1];
            acc[k][2] += (float)buf[k][2]; acc[k][3] += (float)buf[k][3];
        }
    }
}

__device__ __forceinline__ void gather8p(
    const half4v* __restrict__ hs4, const int* __restrict__ csr,
    const int* __restrict__ rowptr, int node0, int n,
    int eg, int fl, int lane, floatx4 acc[8])
{
    int base[8], cc[8], rc[8], idx[8];
    int maxc = 0;
    #pragma unroll
    for (int k = 0; k < 8; k++) {
        int nd = node0 + k;
        int b0 = 0, c0 = 0;
        if (nd < n) { b0 = rowptr[nd]; c0 = rowptr[nd + 1] - b0; }
        base[k] = b0; rc[k] = c0; cc[k] = min(c0, 64);
        maxc = max(maxc, cc[k]);
    }
    #pragma unroll
    for (int k = 0; k < 8; k++)
        idx[k] = (lane < cc[k]) ? __builtin_nontemporal_load(&csr[base[k] + lane]) : 0;

    #pragma unroll
    for (int k = 0; k < 8; k++) { floatx4 z = {0.f, 0.f, 0.f, 0.f}; acc[k] = z; }

    if (eg == 0) {   // self-loops: 8 independent streaming loads
        half4v sv[8];
        #pragma unroll
        for (int k = 0; k < 8; k++) {
            int nd = min(node0 + k, n - 1);
            sv[k] = hs4[(size_t)nd * 32 + fl];
        }
        #pragma unroll
        for (int k = 0; k < 8; k++) {
            if (node0 + k < n) {
                acc[k][0] += (float)sv[k][0]; acc[k][1] += (float)sv[k][1];
                acc[k][2] += (float)sv[k][2]; acc[k][3] += (float)sv[k][3];
            }
        }
    }

    const int rmax = (maxc + 1) >> 1;     // rounds of 2 edges/node
    half4v va[8], vb[8], vc[8];
    g8_issue(hs4, idx, cc, 0, eg, fl, va);
    g8_issue(hs4, idx, cc, 2, eg, fl, vb);
    g8_issue(hs4, idx, cc, 4, eg, fl, vc);

    int s = 0;
    for (; s + 3 < rmax; s += 3) {
        g8_accum(va, cc, (s + 0) * 2, eg, acc);
        g8_issue(hs4, idx, cc, (s + 3) * 2, eg, fl, va);
        g8_accum(vb, cc, (s + 1) * 2, eg, acc);
        g8_issue(hs4, idx, cc, (s + 4) * 2, eg, fl, vb);
        g8_accum(vc, cc, (s + 2) * 2, eg, acc);
        g8_issue(hs4, idx, cc, (s + 5) * 2, eg, fl, vc);
    }
    if (s + 0 < rmax) g8_accum(va, cc, (s + 0) * 2, eg, acc);
    if (s + 1 < rmax) g8_accum(vb, cc, (s + 1) * 2, eg, acc);
    if (s + 2 < rmax) g8_accum(vc, cc, (s + 2) * 2, eg, acc);

    // tails (cnt > 64): essentially never at Poisson(16); simple unit-2 walk
    #pragma unroll
    for (int k = 0; k < 8; k++) {
        if (rc[k] > 64) {
            for (int off = 64; off < rc[k]; off += 64) {
                int m = min(64, rc[k] - off);
                int id2 = (lane < m) ? __builtin_nontemporal_load(&csr[base[k] + off + lane]) : 0;
                for (int j = 0; j < m; j += 2) {
                    int si = __shfl(id2, min(j + eg, m - 1), 64);
                    half4v v = hs4[(size_t)si * 32 + fl];
                    if (j + eg < m) {
                        acc[k][0] += (float)v[0]; acc[k][1] += (float)v[1];
                        acc[k][2] += (float)v[2]; acc[k][3] += (float)v[3];
                    }
                }
            }
        }
    }

    #pragma unroll
    for (int k = 0; k < 8; k++) {
        #pragma unroll
        for (int q = 0; q < 4; q++)
            acc[k][q] += __shfl_xor(acc[k][q], 32, 64);
    }
}

// ---------------- aggmm: fused agg(layer1) + gemm2, 32 nodes/block ---------------
__global__ __launch_bounds__(256, 4) void aggmm_k(
    const __half* __restrict__ hs, const int* __restrict__ rowptr,
    const int* __restrict__ csr, const float* __restrict__ dinv,
    const float* __restrict__ bias, const __half* __restrict__ WT,
    __half* __restrict__ Hout, int n)
{
    __shared__ __half alds[32][136];
    const int tid = threadIdx.x;
    const int wave = tid >> 6, lane = tid & 63;
    const int eg = lane >> 5, fl = lane & 31;
    const int nb0 = blockIdx.x * 32;
    const int node0 = nb0 + wave * 8;

    floatx4 acc[8];
    gather8p((const half4v*)hs, csr, rowptr, node0, n, eg, fl, lane, acc);

    if (eg == 0) {
        #pragma unroll
        for (int k = 0; k < 8; k++) {
            int node = node0 + k;
            half4v h;
            if (node < n) {
                float dv = dinv[node];
                h[0] = (_Float16)fmaxf(dv * acc[k][0] + bias[fl * 4 + 0], 0.f);
                h[1] = (_Float16)fmaxf(dv * acc[k][1] + bias[fl * 4 + 1], 0.f);
                h[2] = (_Float16)fmaxf(dv * acc[k][2] + bias[fl * 4 + 2], 0.f);
                h[3] = (_Float16)fmaxf(dv * acc[k][3] + bias[fl * 4 + 3], 0.f);
            } else {
                h[0] = (_Float16)0.f; h[1] = (_Float16)0.f;
                h[2] = (_Float16)0.f; h[3] = (_Float16)0.f;
            }
            *(half4v*)&alds[wave * 8 + k][fl * 4] = h;
        }
    }
    __syncthreads();

    // 32x128 output: wave w owns col-tiles {2w, 2w+1}, both 16-row tiles
    const int quad = lane >> 4, l15 = lane & 15;
    half8 afr0[4], afr1[4];
    #pragma unroll
    for (int kc = 0; kc < 4; kc++) {
        afr0[kc] = *(const half8*)&alds[l15][kc * 32 + quad * 8];
        afr1[kc] = *(const half8*)&alds[16 + l15][kc * 32 + quad * 8];
    }

    floatx4 o00 = {0.f, 0.f, 0.f, 0.f}, o01 = {0.f, 0.f, 0.f, 0.f};
    floatx4 o10 = {0.f, 0.f, 0.f, 0.f}, o11 = {0.f, 0.f, 0.f, 0.f};
    const int ct0 = wave * 2, ct1 = wave * 2 + 1;
    #pragma unroll
    for (int kc = 0; kc < 4; kc++) {
        half8 b0 = *(const half8*)(WT + (size_t)(ct0 * 16 + l15) * NF + kc * 32 + quad * 8);
        half8 b1 = *(const half8*)(WT + (size_t)(ct1 * 16 + l15) * NF + kc * 32 + quad * 8);
        o00 = __builtin_amdgcn_mfma_f32_16x16x32_f16(afr0[kc], b0, o00, 0, 0, 0);
        o01 = __builtin_amdgcn_mfma_f32_16x16x32_f16(afr0[kc], b1, o01, 0, 0, 0);
        o10 = __builtin_amdgcn_mfma_f32_16x16x32_f16(afr1[kc], b0, o10, 0, 0, 0);
        o11 = __builtin_amdgcn_mfma_f32_16x16x32_f16(afr1[kc], b1, o11, 0, 0, 0);
    }

    #pragma unroll
    for (int r = 0; r < 4; r++) {
        int n0 = nb0 + quad * 4 + r;
        int n1 = n0 + 16;
        if (n0 < n) {
            float s = dinv[n0];
            Hout[(size_t)n0 * NF + ct0 * 16 + l15] = __float2half(o00[r] * s);
            Hout[(size_t)n0 * NF + ct1 * 16 + l15] = __float2half(o01[r] * s);
        }
        if (n1 < n) {
            float s = dinv[n1];
            Hout[(size_t)n1 * NF + ct0 * 16 + l15] = __float2half(o10[r] * s);
            Hout[(size_t)n1 * NF + ct1 * 16 + l15] = __float2half(o11[r] * s);
        }
    }
}

// ---------------- agg4: final aggregate (fp32 out), 32 nodes/block ---------------
__global__ __launch_bounds__(256, 4) void agg4_k(
    const __half* __restrict__ hs, const int* __restrict__ rowptr,
    const int* __restrict__ csr, const float* __restrict__ dinv,
    const float* __restrict__ bias, float* __restrict__ outf, int n)
{
    const int tid = threadIdx.x;
    const int wave = tid >> 6, lane = tid & 63;
    const int eg = lane >> 5, fl = lane & 31;
    const int node0 = blockIdx.x * 32 + wave * 8;

    floatx4 acc[8];
    gather8p((const half4v*)hs, csr, rowptr, node0, n, eg, fl, lane, acc);

    if (eg == 0) {
        #pragma unroll
        for (int k = 0; k < 8; k++) {
            int node = node0 + k;
            if (node < n) {
                float dv = dinv[node];
                floatx4 w;
                w[0] = dv * acc[k][0] + bias[fl * 4 + 0];
                w[1] = dv * acc[k][1] + bias[fl * 4 + 1];
                w[2] = dv * acc[k][2] + bias[fl * 4 + 2];
                w[3] = dv * acc[k][3] + bias[fl * 4 + 3];
                *(floatx4*)(outf + (size_t)node * NF + fl * 4) = w;
            }
        }
    }
}

// ---------------- launch ----------------

extern "C" void kernel_launch(void* const* d_in, const int* in_sizes, int n_in,
                              void* d_out, int out_size, void* d_ws, size_t ws_size,
                              hipStream_t stream) {
    const float* x  = (const float*)d_in[0];
    const int*   ei = (const int*)d_in[1];
    const float* W1 = (const float*)d_in[2];
    const float* b1 = (const float*)d_in[3];
    const float* W2 = (const float*)d_in[4];
    const float* b2 = (const float*)d_in[5];
    float* out = (float*)d_out;

    const int N = in_sizes[0] / NF;   // 50000
    const int E = in_sizes[1] / 2;    // 800000
    const int* src = ei;
    const int* dst = ei + E;

    char* ws = (char*)d_ws;
    size_t off = 0;
    auto alloc = [&](size_t bytes) {
        void* p = ws + off;
        off += bytes;
        off = (off + 63) & ~(size_t)63;
        return p;
    };
    unsigned char* pcnt = (unsigned char*)alloc((size_t)KC * N);  // counts->coff
    int*    rowptr  = (int*)alloc((size_t)(N + 1) * 4);   // local prefixes
    int*    rowptr2 = (int*)alloc((size_t)(N + 1) * 4);   // corrected (agg uses)
    int*    csr     = (int*)alloc((size_t)E * 4);
    float*  dinv    = (float*)alloc((size_t)N * 4);
    int*    bsum    = (int*)alloc((size_t)256 * 4);
    __half* WT1     = (__half*)alloc((size_t)NF * NF * 2);
    __half* WT2     = (__half*)alloc((size_t)NF * NF * 2);
    __half* H16     = (__half*)alloc((size_t)N * NF * 2);
    __half* A16     = (__half*)alloc((size_t)N * NF * 2);

    int nb  = (N + 255) / 256;                 // 196 (<=256)
    int Ec  = (((E + KC - 1) / KC) + 3) & ~3;  // chunk size, multiple of 4
    int GB2 = (N + 127) / 128;                 // gemm1 blocks (512 thr)
    int fb  = (N + 31) / 32;                   // agg blocks (32 nodes each)

    count2_k<<<KC * NPART, 512, 0, stream>>>(dst, pcnt, E, N, Ec);
    pscan2_k<<<nb + 128, 256, 0, stream>>>(pcnt, dinv, rowptr, bsum, N, N, nb,
                                           W1, W2, WT1, WT2);
    mid_k<<<GB2 + KC * NPART, 512, 0, stream>>>(src, dst, rowptr, pcnt, bsum,
                                                rowptr2, csr, E, N, Ec, nb,
                                                x, WT1, dinv, H16, GB2);
    // fused layer-1 aggregate + layer-2 GEMM (depth-3 pipelined gather)
    aggmm_k<<<fb, 256, 0, stream>>>(H16, rowptr2, csr, dinv, b1, WT2, A16, N);
    // final aggregate -> fp32 output
    agg4_k<<<fb, 256, 0, stream>>>(A16, rowptr2, csr, dinv, b2, out, N);
}

// Round 5
// 468.110 us; speedup vs baseline: 2.3446x; 2.3446x over previous
//
#include <hip/hip_runtime.h>
#include <hip/hip_fp16.h>

#define NF 128    // feature dim, fixed by the problem
#define KC 64     // edge chunks
#define NPART 4   // node partitions (N/4 ints must fit LDS: 12500*4B = 50KB)
#define NPMAX 12544

typedef _Float16 half8  __attribute__((ext_vector_type(8)));
typedef _Float16 half4v __attribute__((ext_vector_type(4)));
typedef float    floatx4 __attribute__((ext_vector_type(4)));

// ---------------- count2: LDS histogram per (chunk, partition) -------------------
__global__ __launch_bounds__(512) void count2_k(
    const int* __restrict__ dst, unsigned char* __restrict__ pcnt,
    int E, int N, int Ec)
{
    __shared__ int lcnt[NPMAX];
    const int p = blockIdx.x & 3, c = blockIdx.x >> 2;
    const int Np = (N + 3) >> 2;
    const int lo = p * Np, hi = min(lo + Np, N);
    const int sz = hi - lo;
    for (int i = threadIdx.x; i < sz; i += 512) lcnt[i] = 0;
    __syncthreads();

    const int e0 = c * Ec, e1 = min(e0 + Ec, E);
    for (int e = e0 + (int)threadIdx.x * 4; e + 3 < e1; e += 512 * 4) {
        int4 d = *(const int4*)(dst + e);
        if (d.x >= lo && d.x < hi) atomicAdd(&lcnt[d.x - lo], 1);
        if (d.y >= lo && d.y < hi) atomicAdd(&lcnt[d.y - lo], 1);
        if (d.z >= lo && d.z < hi) atomicAdd(&lcnt[d.z - lo], 1);
        if (d.w >= lo && d.w < hi) atomicAdd(&lcnt[d.w - lo], 1);
    }
    int rem0 = e0 + ((e1 - e0) & ~3);
    for (int e = rem0 + (int)threadIdx.x; e < e1; e += 512) {
        int d = dst[e];
        if (d >= lo && d < hi) atomicAdd(&lcnt[d - lo], 1);
    }
    __syncthreads();
    for (int i = threadIdx.x; i < sz; i += 512)
        pcnt[(size_t)c * N + lo + i] = (unsigned char)lcnt[i];
}

// ---------------- pscan2 (+fused W-transpose) ------------------------------------
__global__ __launch_bounds__(256) void pscan2_k(
    unsigned char* __restrict__ pcnt, float* __restrict__ dinv,
    int* __restrict__ rowptr, int* __restrict__ blocksum, int n, int N, int nb,
    const float* __restrict__ W1, const float* __restrict__ W2,
    __half* __restrict__ WT1, __half* __restrict__ WT2)
{
    if ((int)blockIdx.x >= nb) {
        int idx = ((int)blockIdx.x - nb) * 256 + threadIdx.x;   // 0..32767
        const float* W = (idx < 16384) ? W1 : W2;
        __half* WT     = (idx < 16384) ? WT1 : WT2;
        int j = idx & 16383;
        int nn = j & 127, k = j >> 7;
        WT[nn * NF + k] = __float2half(W[k * NF + nn]);
        return;
    }
    __shared__ int sm[256];
    int tid = threadIdx.x;
    int bin = blockIdx.x * 256 + tid;
    int total = 0;
    if (bin < n) {
        #pragma unroll 4
        for (int c = 0; c < KC; c++) {
            size_t o = (size_t)c * N + bin;
            int v = pcnt[o];
            pcnt[o] = (unsigned char)total;   // exclusive chunk prefix (coff)
            total += v;
        }
        dinv[bin] = rsqrtf((float)total + 1.0f);  // +1 = self-loop
    }
    sm[tid] = total;
    __syncthreads();
    #pragma unroll
    for (int d = 1; d < 256; d <<= 1) {
        int t = (tid >= d) ? sm[tid - d] : 0;
        __syncthreads();
        sm[tid] += t;
        __syncthreads();
    }
    if (bin < n) rowptr[bin] = sm[tid] - total;    // local exclusive prefix
    if (tid == 255) blocksum[blockIdx.x] = sm[255];
}

// ---------------- MFMA GEMM body (512 threads, 128 rows/block) -------------------
template<bool F32IN>
__device__ __forceinline__ void gemm_body512(
    const void* __restrict__ Xv, const __half* __restrict__ WT,
    const float* __restrict__ dinv, __half* __restrict__ out, int M, int bid,
    __half (*wlds)[136])
{
    const int tid = threadIdx.x;
    {   // stage WT (128x128 halves): 4 threads/row, 32 halves each
        int r = tid >> 2;
        int c0 = (tid & 3) * 32;
        const half8* s = (const half8*)(WT + (size_t)r * NF + c0);
        half8* d = (half8*)&wlds[r][c0];
        #pragma unroll
        for (int j = 0; j < 4; j++) d[j] = s[j];
    }
    __syncthreads();

    const int wave = tid >> 6, lane = tid & 63;
    const int quad = lane >> 4, l15 = lane & 15;
    const int rowA = bid * 128 + wave * 16 + l15;
    const int rowc = (rowA < M) ? rowA : (M - 1);

    half8 afr[4];
    if (F32IN) {
        const float* X = (const float*)Xv;
        #pragma unroll
        for (int kc = 0; kc < 4; kc++) {
            const floatx4* p = (const floatx4*)(X + (size_t)rowc * NF + kc * 32 + quad * 8);
            floatx4 u = p[0], v = p[1];
            half8 a;
            a[0] = (_Float16)u[0]; a[1] = (_Float16)u[1];
            a[2] = (_Float16)u[2]; a[3] = (_Float16)u[3];
            a[4] = (_Float16)v[0]; a[5] = (_Float16)v[1];
            a[6] = (_Float16)v[2]; a[7] = (_Float16)v[3];
            afr[kc] = a;
        }
    } else {
        const __half* X = (const __half*)Xv;
        #pragma unroll
        for (int kc = 0; kc < 4; kc++)
            afr[kc] = *(const half8*)(X + (size_t)rowc * NF + kc * 32 + quad * 8);
    }

    floatx4 acc[8];
    #pragma unroll
    for (int ct = 0; ct < 8; ct++) { floatx4 z = {0.f, 0.f, 0.f, 0.f}; acc[ct] = z; }

    #pragma unroll
    for (int kc = 0; kc < 4; kc++) {
        #pragma unroll
        for (int ct = 0; ct < 8; ct++) {
            half8 b = *(const half8*)&wlds[ct * 16 + l15][kc * 32 + quad * 8];
            acc[ct] = __builtin_amdgcn_mfma_f32_16x16x32_f16(afr[kc], b, acc[ct], 0, 0, 0);
        }
    }

    const int orow0 = bid * 128 + wave * 16 + quad * 4;
    #pragma unroll
    for (int r = 0; r < 4; r++) {
        int orow = orow0 + r;
        if (orow < M) {
            float s = dinv[orow];
            #pragma unroll
            for (int ct = 0; ct < 8; ct++)
                out[(size_t)orow * NF + ct * 16 + l15] = __float2half(acc[ct][r] * s);
        }
    }
}

// ---------------- mid_k: fused gemm1 + fill (+add_off) ---------------------------
__global__ __launch_bounds__(512) void mid_k(
    const int* __restrict__ src, const int* __restrict__ dst,
    const int* __restrict__ rowptr, const unsigned char* __restrict__ coff,
    const int* __restrict__ blocksum, int* __restrict__ rowptr2,
    int* __restrict__ csr, int E, int N, int Ec, int nb,
    const float* __restrict__ X, const __half* __restrict__ WT,
    const float* __restrict__ dinv, __half* __restrict__ H, int GB2)
{
    __shared__ __align__(16) char smem[NPMAX * 4 + 1024];   // 51.2KB union
    const int tid = threadIdx.x;
    if ((int)blockIdx.x < GB2) {
        gemm_body512<true>(X, WT, dinv, H, N, blockIdx.x, (__half(*)[136])smem);
        return;
    }
    int* lcur = (int*)smem;
    int* pref = (int*)(smem + NPMAX * 4);

    const int b = blockIdx.x - GB2;
    const int p = b & 3, c = b >> 2;
    const int Np = (N + 3) >> 2;
    const int lo = p * Np, hi = min(lo + Np, N);
    const int sz = hi - lo;

    // exclusive prefix of blocksum[0..nb) in pref
    int v = (tid < nb) ? blocksum[tid] : 0;
    if (tid < 256) pref[tid] = v;
    __syncthreads();
    #pragma unroll
    for (int d = 1; d < 256; d <<= 1) {
        int t = (tid < 256 && tid >= d) ? pref[tid - d] : 0;
        __syncthreads();
        if (tid < 256) pref[tid] += t;
        __syncthreads();
    }
    if (tid < 256) pref[tid] -= v;
    __syncthreads();

    for (int i = tid; i < sz; i += 512) {
        int bin = lo + i;
        int r = rowptr[bin] + pref[bin >> 8] + (int)coff[(size_t)c * N + bin];
        lcur[i] = r;
        if (c == 0) rowptr2[bin] = r;
    }
    if (c == 0 && p == 0 && tid == 0) rowptr2[N] = E;
    __syncthreads();

    const int e0 = c * Ec, e1 = min(e0 + Ec, E);
    for (int e = e0 + tid * 4; e + 3 < e1; e += 512 * 4) {
        int4 d = *(const int4*)(dst + e);
        int4 s = *(const int4*)(src + e);
        if (d.x >= lo && d.x < hi) csr[atomicAdd(&lcur[d.x - lo], 1)] = s.x;
        if (d.y >= lo && d.y < hi) csr[atomicAdd(&lcur[d.y - lo], 1)] = s.y;
        if (d.z >= lo && d.z < hi) csr[atomicAdd(&lcur[d.z - lo], 1)] = s.z;
        if (d.w >= lo && d.w < hi) csr[atomicAdd(&lcur[d.w - lo], 1)] = s.w;
    }
    int rem0 = e0 + ((e1 - e0) & ~3);
    for (int e = rem0 + tid; e < e1; e += 512) {
        int d = dst[e];
        if (d >= lo && d < hi) csr[atomicAdd(&lcur[d - lo], 1)] = src[e];
    }
}

// ---------------- spill-proof depth-2 pipelined gather ---------------------------
// R4's array-through-pointer form went to scratch (WRITE_SIZE 1.39GB). This
// version uses ONLY individually named registers (macro-generated), so SROA
// cannot fail. Depth-2 A/B round buffers: accumulate round s while rounds
// s+1/s+2 (16 loads) are in flight. 8 nodes/wave, 2 edges/node/round.
#define G8_SETUP(K)                                                          \
    int cc##K; int ix##K;                                                    \
    {                                                                        \
        int bs = 0, rcv = 0;                                                 \
        if (node0 + K < n) { bs = rowptr[node0 + K];                         \
                             rcv = rowptr[node0 + K + 1] - bs; }             \
        cc##K = min(rcv, 64);                                                \
        anytail |= (rcv > 64);                                               \
        maxc = max(maxc, cc##K);                                             \
        ix##K = (lane < cc##K)                                               \
              ? __builtin_nontemporal_load(&csr[bs + lane]) : 0;             \
    }

#define G8_ISS1(X, K, s2)                                                    \
    { int t = min((s2) + eg, cc##K - 1); t = (t < 0) ? 0 : t;                \
      v##X##K = hs4[(size_t)__shfl(ix##K, t, 64) * 32 + fl]; }

#define G8_ISSUE(X, s)                                                       \
    { const int s2_ = (s) * 2;                                               \
      G8_ISS1(X, 0, s2_) G8_ISS1(X, 1, s2_) G8_ISS1(X, 2, s2_)               \
      G8_ISS1(X, 3, s2_) G8_ISS1(X, 4, s2_) G8_ISS1(X, 5, s2_)               \
      G8_ISS1(X, 6, s2_) G8_ISS1(X, 7, s2_) }

#define G8_AC1(X, K, s2)                                                     \
    if ((s2) + eg < cc##K) {                                                 \
        a##K[0] += (float)v##X##K[0]; a##K[1] += (float)v##X##K[1];          \
        a##K[2] += (float)v##X##K[2]; a##K[3] += (float)v##X##K[3]; }

#define G8_ACC(X, s)                                                         \
    { const int s2_ = (s) * 2;                                               \
      G8_AC1(X, 0, s2_) G8_AC1(X, 1, s2_) G8_AC1(X, 2, s2_)                  \
      G8_AC1(X, 3, s2_) G8_AC1(X, 4, s2_) G8_AC1(X, 5, s2_)                  \
      G8_AC1(X, 6, s2_) G8_AC1(X, 7, s2_) }

#define G8_SELF(K)                                                           \
    { int nd = min(node0 + K, n - 1);                                        \
      half4v sl = hs4[(size_t)nd * 32 + fl];                                 \
      if (node0 + K < n) {                                                   \
          a##K[0] += (float)sl[0]; a##K[1] += (float)sl[1];                  \
          a##K[2] += (float)sl[2]; a##K[3] += (float)sl[3]; } }

#define G8_TAIL(K)                                                           \
    {                                                                        \
        int bs = rowptr[node0 + K];                                          \
        int rcv = rowptr[node0 + K + 1] - bs;                                \
        for (int off = 64; off < rcv; off += 64) {                           \
            int m = min(64, rcv - off);                                      \
            int id2 = (lane < m) ? csr[bs + off + lane] : 0;                 \
            for (int j = 0; j < m; j += 2) {                                 \
                int si = __shfl(id2, min(j + eg, m - 1), 64);                \
                half4v vv = hs4[(size_t)si * 32 + fl];                       \
                if (j + eg < m) {                                            \
                    a##K[0] += (float)vv[0]; a##K[1] += (float)vv[1];        \
                    a##K[2] += (float)vv[2]; a##K[3] += (float)vv[3]; }      \
            }                                                                \
        }                                                                    \
    }

#define G8_RED(K)                                                            \
    { a##K[0] += __shfl_xor(a##K[0], 32, 64);                                \
      a##K[1] += __shfl_xor(a##K[1], 32, 64);                                \
      a##K[2] += __shfl_xor(a##K[2], 32, 64);                                \
      a##K[3] += __shfl_xor(a##K[3], 32, 64); }

// Body macro: declares and fills a0..a7 (each lane-half pre-reduced, then
// xor-combined so eg==0 lanes hold the full sums).
#define GATHER8_BODY(hs4, csr, rowptr, node0, n, eg, fl, lane)               \
    floatx4 a0 = {0,0,0,0}, a1 = {0,0,0,0}, a2 = {0,0,0,0}, a3 = {0,0,0,0};  \
    floatx4 a4 = {0,0,0,0}, a5 = {0,0,0,0}, a6 = {0,0,0,0}, a7 = {0,0,0,0};  \
    {                                                                        \
        int maxc = 0; bool anytail = false;                                  \
        G8_SETUP(0) G8_SETUP(1) G8_SETUP(2) G8_SETUP(3)                      \
        G8_SETUP(4) G8_SETUP(5) G8_SETUP(6) G8_SETUP(7)                      \
        if (eg == 0) {                                                       \
            G8_SELF(0) G8_SELF(1) G8_SELF(2) G8_SELF(3)                      \
            G8_SELF(4) G8_SELF(5) G8_SELF(6) G8_SELF(7)                      \
        }                                                                    \
        half4v vA0, vA1, vA2, vA3, vA4, vA5, vA6, vA7;                       \
        half4v vB0, vB1, vB2, vB3, vB4, vB5, vB6, vB7;                       \
        const int rmax = (maxc + 1) >> 1;                                    \
        G8_ISSUE(A, 0)                                                       \
        G8_ISSUE(B, 1)                                                       \
        int s = 0;                                                           \
        for (; s + 2 < rmax; s += 2) {                                       \
            G8_ACC(A, s)     G8_ISSUE(A, s + 2)                              \
            G8_ACC(B, s + 1) G8_ISSUE(B, s + 3)                              \
        }                                                                    \
        if (s < rmax)     { G8_ACC(A, s) }                                   \
        if (s + 1 < rmax) { G8_ACC(B, s + 1) }                               \
        if (anytail) {                                                       \
            G8_TAIL(0) G8_TAIL(1) G8_TAIL(2) G8_TAIL(3)                      \
            G8_TAIL(4) G8_TAIL(5) G8_TAIL(6) G8_TAIL(7)                      \
        }                                                                    \
        G8_RED(0) G8_RED(1) G8_RED(2) G8_RED(3)                              \
        G8_RED(4) G8_RED(5) G8_RED(6) G8_RED(7)                              \
    }

// ---------------- aggmm: fused agg(layer1) + gemm2, 32 nodes/block ---------------
__global__ __launch_bounds__(256, 4) void aggmm_k(
    const __half* __restrict__ hs, const int* __restrict__ rowptr,
    const int* __restrict__ csr, const float* __restrict__ dinv,
    const float* __restrict__ bias, const __half* __restrict__ WT,
    __half* __restrict__ Hout, int n)
{
    __shared__ __half alds[32][136];
    const int tid = threadIdx.x;
    const int wave = tid >> 6, lane = tid & 63;
    const int eg = lane >> 5, fl = lane & 31;
    const int nb0 = blockIdx.x * 32;
    const int node0 = nb0 + wave * 8;
    const half4v* hs4 = (const half4v*)hs;

    GATHER8_BODY(hs4, csr, rowptr, node0, n, eg, fl, lane)

    if (eg == 0) {
        const float bv0 = bias[fl * 4 + 0], bv1 = bias[fl * 4 + 1];
        const float bv2 = bias[fl * 4 + 2], bv3 = bias[fl * 4 + 3];
        #define STORE_ALDS(K)                                                 \
        {                                                                     \
            int node = node0 + K;                                             \
            half4v h;                                                         \
            if (node < n) {                                                   \
                float dv = dinv[node];                                        \
                h[0] = (_Float16)fmaxf(dv * a##K[0] + bv0, 0.f);              \
                h[1] = (_Float16)fmaxf(dv * a##K[1] + bv1, 0.f);              \
                h[2] = (_Float16)fmaxf(dv * a##K[2] + bv2, 0.f);              \
                h[3] = (_Float16)fmaxf(dv * a##K[3] + bv3, 0.f);              \
            } else {                                                          \
                h[0] = (_Float16)0.f; h[1] = (_Float16)0.f;                   \
                h[2] = (_Float16)0.f; h[3] = (_Float16)0.f;                   \
            }                                                                 \
            *(half4v*)&alds[wave * 8 + K][fl * 4] = h;                        \
        }
        STORE_ALDS(0) STORE_ALDS(1) STORE_ALDS(2) STORE_ALDS(3)
        STORE_ALDS(4) STORE_ALDS(5) STORE_ALDS(6) STORE_ALDS(7)
        #undef STORE_ALDS
    }
    __syncthreads();

    // 32x128 output: wave w owns col-tiles {2w, 2w+1}, both 16-row tiles
    const int quad = lane >> 4, l15 = lane & 15;
    half8 afr0[4], afr1[4];
    #pragma unroll
    for (int kc = 0; kc < 4; kc++) {
        afr0[kc] = *(const half8*)&alds[l15][kc * 32 + quad * 8];
        afr1[kc] = *(const half8*)&alds[16 + l15][kc * 32 + quad * 8];
    }

    floatx4 o00 = {0.f, 0.f, 0.f, 0.f}, o01 = {0.f, 0.f, 0.f, 0.f};
    floatx4 o10 = {0.f, 0.f, 0.f, 0.f}, o11 = {0.f, 0.f, 0.f, 0.f};
    const int ct0 = wave * 2, ct1 = wave * 2 + 1;
    #pragma unroll
    for (int kc = 0; kc < 4; kc++) {
        half8 b0 = *(const half8*)(WT + (size_t)(ct0 * 16 + l15) * NF + kc * 32 + quad * 8);
        half8 b1 = *(const half8*)(WT + (size_t)(ct1 * 16 + l15) * NF + kc * 32 + quad * 8);
        o00 = __builtin_amdgcn_mfma_f32_16x16x32_f16(afr0[kc], b0, o00, 0, 0, 0);
        o01 = __builtin_amdgcn_mfma_f32_16x16x32_f16(afr0[kc], b1, o01, 0, 0, 0);
        o10 = __builtin_amdgcn_mfma_f32_16x16x32_f16(afr1[kc], b0, o10, 0, 0, 0);
        o11 = __builtin_amdgcn_mfma_f32_16x16x32_f16(afr1[kc], b1, o11, 0, 0, 0);
    }

    #pragma unroll
    for (int r = 0; r < 4; r++) {
        int n0 = nb0 + quad * 4 + r;
        int n1 = n0 + 16;
        if (n0 < n) {
            float s = dinv[n0];
            Hout[(size_t)n0 * NF + ct0 * 16 + l15] = __float2half(o00[r] * s);
            Hout[(size_t)n0 * NF + ct1 * 16 + l15] = __float2half(o01[r] * s);
        }
        if (n1 < n) {
            float s = dinv[n1];
            Hout[(size_t)n1 * NF + ct0 * 16 + l15] = __float2half(o10[r] * s);
            Hout[(size_t)n1 * NF + ct1 * 16 + l15] = __float2half(o11[r] * s);
        }
    }
}

// ---------------- agg4: final aggregate (fp32 out), 32 nodes/block ---------------
__global__ __launch_bounds__(256, 4) void agg4_k(
    const __half* __restrict__ hs, const int* __restrict__ rowptr,
    const int* __restrict__ csr, const float* __restrict__ dinv,
    const float* __restrict__ bias, float* __restrict__ outf, int n)
{
    const int tid = threadIdx.x;
    const int wave = tid >> 6, lane = tid & 63;
    const int eg = lane >> 5, fl = lane & 31;
    const int node0 = blockIdx.x * 32 + wave * 8;
    const half4v* hs4 = (const half4v*)hs;

    GATHER8_BODY(hs4, csr, rowptr, node0, n, eg, fl, lane)

    if (eg == 0) {
        const float bv0 = bias[fl * 4 + 0], bv1 = bias[fl * 4 + 1];
        const float bv2 = bias[fl * 4 + 2], bv3 = bias[fl * 4 + 3];
        #define STORE_OUT(K)                                                  \
        {                                                                     \
            int node = node0 + K;                                             \
            if (node < n) {                                                   \
                float dv = dinv[node];                                        \
                floatx4 w;                                                    \
                w[0] = dv * a##K[0] + bv0;                                    \
                w[1] = dv * a##K[1] + bv1;                                    \
                w[2] = dv * a##K[2] + bv2;                                    \
                w[3] = dv * a##K[3] + bv3;                                    \
                *(floatx4*)(outf + (size_t)node * NF + fl * 4) = w;           \
            }                                                                 \
        }
        STORE_OUT(0) STORE_OUT(1) STORE_OUT(2) STORE_OUT(3)
        STORE_OUT(4) STORE_OUT(5) STORE_OUT(6) STORE_OUT(7)
        #undef STORE_OUT
    }
}

// ---------------- launch ----------------

extern "C" void kernel_launch(void* const* d_in, const int* in_sizes, int n_in,
                              void* d_out, int out_size, void* d_ws, size_t ws_size,
                              hipStream_t stream) {
    const float* x  = (const float*)d_in[0];
    const int*   ei = (const int*)d_in[1];
    const float* W1 = (const float*)d_in[2];
    const float* b1 = (const float*)d_in[3];
    const float* W2 = (const float*)d_in[4];
    const float* b2 = (const float*)d_in[5];
    float* out = (float*)d_out;

    const int N = in_sizes[0] / NF;   // 50000
    const int E = in_sizes[1] / 2;    // 800000
    const int* src = ei;
    const int* dst = ei + E;

    char* ws = (char*)d_ws;
    size_t off = 0;
    auto alloc = [&](size_t bytes) {
        void* p = ws + off;
        off += bytes;
        off = (off + 63) & ~(size_t)63;
        return p;
    };
    unsigned char* pcnt = (unsigned char*)alloc((size_t)KC * N);  // counts->coff
    int*    rowptr  = (int*)alloc((size_t)(N + 1) * 4);   // local prefixes
    int*    rowptr2 = (int*)alloc((size_t)(N + 1) * 4);   // corrected (agg uses)
    int*    csr     = (int*)alloc((size_t)E * 4);
    float*  dinv    = (float*)alloc((size_t)N * 4);
    int*    bsum    = (int*)alloc((size_t)256 * 4);
    __half* WT1     = (__half*)alloc((size_t)NF * NF * 2);
    __half* WT2     = (__half*)alloc((size_t)NF * NF * 2);
    __half* H16     = (__half*)alloc((size_t)N * NF * 2);
    __half* A16     = (__half*)alloc((size_t)N * NF * 2);

    int nb  = (N + 255) / 256;                 // 196 (<=256)
    int Ec  = (((E + KC - 1) / KC) + 3) & ~3;  // chunk size, multiple of 4
    int GB2 = (N + 127) / 128;                 // gemm1 blocks (512 thr)
    int fb  = (N + 31) / 32;                   // agg blocks (32 nodes each)

    count2_k<<<KC * NPART, 512, 0, stream>>>(dst, pcnt, E, N, Ec);
    pscan2_k<<<nb + 128, 256, 0, stream>>>(pcnt, dinv, rowptr, bsum, N, N, nb,
                                           W1, W2, WT1, WT2);
    mid_k<<<GB2 + KC * NPART, 512, 0, stream>>>(src, dst, rowptr, pcnt, bsum,
                                                rowptr2, csr, E, N, Ec, nb,
                                                x, WT1, dinv, H16, GB2);
    // fused layer-1 aggregate + layer-2 GEMM (spill-proof depth-2 pipeline)
    aggmm_k<<<fb, 256, 0, stream>>>(H16, rowptr2, csr, dinv, b1, WT2, A16, N);
    // final aggregate -> fp32 output
    agg4_k<<<fb, 256, 0, stream>>>(A16, rowptr2, csr, dinv, b2, out, N);
}

// Round 6
// 203.885 us; speedup vs baseline: 5.3831x; 2.2960x over previous
//
#include <hip/hip_runtime.h>
#include <hip/hip_fp16.h>

#define NF 128    // feature dim, fixed by the problem
#define KC 64     // edge chunks
#define NPART 4   // node partitions (N/4 ints must fit LDS: 12500*4B = 50KB)
#define NPMAX 12544

typedef _Float16 half8  __attribute__((ext_vector_type(8)));
typedef _Float16 half4v __attribute__((ext_vector_type(4)));
typedef float    floatx4 __attribute__((ext_vector_type(4)));

// ---------------- count2: LDS histogram per (chunk, partition) -------------------
__global__ __launch_bounds__(512) void count2_k(
    const int* __restrict__ dst, unsigned char* __restrict__ pcnt,
    int E, int N, int Ec)
{
    __shared__ int lcnt[NPMAX];
    const int p = blockIdx.x & 3, c = blockIdx.x >> 2;
    const int Np = (N + 3) >> 2;
    const int lo = p * Np, hi = min(lo + Np, N);
    const int sz = hi - lo;
    for (int i = threadIdx.x; i < sz; i += 512) lcnt[i] = 0;
    __syncthreads();

    const int e0 = c * Ec, e1 = min(e0 + Ec, E);
    for (int e = e0 + (int)threadIdx.x * 4; e + 3 < e1; e += 512 * 4) {
        int4 d = *(const int4*)(dst + e);
        if (d.x >= lo && d.x < hi) atomicAdd(&lcnt[d.x - lo], 1);
        if (d.y >= lo && d.y < hi) atomicAdd(&lcnt[d.y - lo], 1);
        if (d.z >= lo && d.z < hi) atomicAdd(&lcnt[d.z - lo], 1);
        if (d.w >= lo && d.w < hi) atomicAdd(&lcnt[d.w - lo], 1);
    }
    int rem0 = e0 + ((e1 - e0) & ~3);
    for (int e = rem0 + (int)threadIdx.x; e < e1; e += 512) {
        int d = dst[e];
        if (d >= lo && d < hi) atomicAdd(&lcnt[d - lo], 1);
    }
    __syncthreads();
    for (int i = threadIdx.x; i < sz; i += 512)
        pcnt[(size_t)c * N + lo + i] = (unsigned char)lcnt[i];
}

// ---------------- pscan2 (+fused W-transpose) ------------------------------------
__global__ __launch_bounds__(256) void pscan2_k(
    unsigned char* __restrict__ pcnt, float* __restrict__ dinv,
    int* __restrict__ rowptr, int* __restrict__ blocksum, int n, int N, int nb,
    const float* __restrict__ W1, const float* __restrict__ W2,
    __half* __restrict__ WT1, __half* __restrict__ WT2)
{
    if ((int)blockIdx.x >= nb) {
        int idx = ((int)blockIdx.x - nb) * 256 + threadIdx.x;   // 0..32767
        const float* W = (idx < 16384) ? W1 : W2;
        __half* WT     = (idx < 16384) ? WT1 : WT2;
        int j = idx & 16383;
        int nn = j & 127, k = j >> 7;
        WT[nn * NF + k] = __float2half(W[k * NF + nn]);
        return;
    }
    __shared__ int sm[256];
    int tid = threadIdx.x;
    int bin = blockIdx.x * 256 + tid;
    int total = 0;
    if (bin < n) {
        #pragma unroll 4
        for (int c = 0; c < KC; c++) {
            size_t o = (size_t)c * N + bin;
            int v = pcnt[o];
            pcnt[o] = (unsigned char)total;   // exclusive chunk prefix (coff)
            total += v;
        }
        dinv[bin] = rsqrtf((float)total + 1.0f);  // +1 = self-loop
    }
    sm[tid] = total;
    __syncthreads();
    #pragma unroll
    for (int d = 1; d < 256; d <<= 1) {
        int t = (tid >= d) ? sm[tid - d] : 0;
        __syncthreads();
        sm[tid] += t;
        __syncthreads();
    }
    if (bin < n) rowptr[bin] = sm[tid] - total;    // local exclusive prefix
    if (tid == 255) blocksum[blockIdx.x] = sm[255];
}

// ---------------- MFMA GEMM body (512 threads, 128 rows/block) -------------------
template<bool F32IN>
__device__ __forceinline__ void gemm_body512(
    const void* __restrict__ Xv, const __half* __restrict__ WT,
    const float* __restrict__ dinv, __half* __restrict__ out, int M, int bid,
    __half (*wlds)[136])
{
    const int tid = threadIdx.x;
    {   // stage WT (128x128 halves): 4 threads/row, 32 halves each
        int r = tid >> 2;
        int c0 = (tid & 3) * 32;
        const half8* s = (const half8*)(WT + (size_t)r * NF + c0);
        half8* d = (half8*)&wlds[r][c0];
        #pragma unroll
        for (int j = 0; j < 4; j++) d[j] = s[j];
    }
    __syncthreads();

    const int wave = tid >> 6, lane = tid & 63;
    const int quad = lane >> 4, l15 = lane & 15;
    const int rowA = bid * 128 + wave * 16 + l15;
    const int rowc = (rowA < M) ? rowA : (M - 1);

    half8 afr[4];
    if (F32IN) {
        const float* X = (const float*)Xv;
        #pragma unroll
        for (int kc = 0; kc < 4; kc++) {
            const floatx4* p = (const floatx4*)(X + (size_t)rowc * NF + kc * 32 + quad * 8);
            floatx4 u = p[0], v = p[1];
            half8 a;
            a[0] = (_Float16)u[0]; a[1] = (_Float16)u[1];
            a[2] = (_Float16)u[2]; a[3] = (_Float16)u[3];
            a[4] = (_Float16)v[0]; a[5] = (_Float16)v[1];
            a[6] = (_Float16)v[2]; a[7] = (_Float16)v[3];
            afr[kc] = a;
        }
    } else {
        const __half* X = (const __half*)Xv;
        #pragma unroll
        for (int kc = 0; kc < 4; kc++)
            afr[kc] = *(const half8*)(X + (size_t)rowc * NF + kc * 32 + quad * 8);
    }

    floatx4 acc[8];
    #pragma unroll
    for (int ct = 0; ct < 8; ct++) { floatx4 z = {0.f, 0.f, 0.f, 0.f}; acc[ct] = z; }

    #pragma unroll
    for (int kc = 0; kc < 4; kc++) {
        #pragma unroll
        for (int ct = 0; ct < 8; ct++) {
            half8 b = *(const half8*)&wlds[ct * 16 + l15][kc * 32 + quad * 8];
            acc[ct] = __builtin_amdgcn_mfma_f32_16x16x32_f16(afr[kc], b, acc[ct], 0, 0, 0);
        }
    }

    const int orow0 = bid * 128 + wave * 16 + quad * 4;
    #pragma unroll
    for (int r = 0; r < 4; r++) {
        int orow = orow0 + r;
        if (orow < M) {
            float s = dinv[orow];
            #pragma unroll
            for (int ct = 0; ct < 8; ct++)
                out[(size_t)orow * NF + ct * 16 + l15] = __float2half(acc[ct][r] * s);
        }
    }
}

// ---------------- mid_k: fused gemm1 + fill (+add_off) ---------------------------
__global__ __launch_bounds__(512) void mid_k(
    const int* __restrict__ src, const int* __restrict__ dst,
    const int* __restrict__ rowptr, const unsigned char* __restrict__ coff,
    const int* __restrict__ blocksum, int* __restrict__ rowptr2,
    int* __restrict__ csr, int E, int N, int Ec, int nb,
    const float* __restrict__ X, const __half* __restrict__ WT,
    const float* __restrict__ dinv, __half* __restrict__ H, int GB2)
{
    __shared__ __align__(16) char smem[NPMAX * 4 + 1024];   // 51.2KB union
    const int tid = threadIdx.x;
    if ((int)blockIdx.x < GB2) {
        gemm_body512<true>(X, WT, dinv, H, N, blockIdx.x, (__half(*)[136])smem);
        return;
    }
    int* lcur = (int*)smem;
    int* pref = (int*)(smem + NPMAX * 4);

    const int b = blockIdx.x - GB2;
    const int p = b & 3, c = b >> 2;
    const int Np = (N + 3) >> 2;
    const int lo = p * Np, hi = min(lo + Np, N);
    const int sz = hi - lo;

    // exclusive prefix of blocksum[0..nb) in pref
    int v = (tid < nb) ? blocksum[tid] : 0;
    if (tid < 256) pref[tid] = v;
    __syncthreads();
    #pragma unroll
    for (int d = 1; d < 256; d <<= 1) {
        int t = (tid < 256 && tid >= d) ? pref[tid - d] : 0;
        __syncthreads();
        if (tid < 256) pref[tid] += t;
        __syncthreads();
    }
    if (tid < 256) pref[tid] -= v;
    __syncthreads();

    for (int i = tid; i < sz; i += 512) {
        int bin = lo + i;
        int r = rowptr[bin] + pref[bin >> 8] + (int)coff[(size_t)c * N + bin];
        lcur[i] = r;
        if (c == 0) rowptr2[bin] = r;
    }
    if (c == 0 && p == 0 && tid == 0) rowptr2[N] = E;
    __syncthreads();

    const int e0 = c * Ec, e1 = min(e0 + Ec, E);
    for (int e = e0 + tid * 4; e + 3 < e1; e += 512 * 4) {
        int4 d = *(const int4*)(dst + e);
        int4 s = *(const int4*)(src + e);
        if (d.x >= lo && d.x < hi) csr[atomicAdd(&lcur[d.x - lo], 1)] = s.x;
        if (d.y >= lo && d.y < hi) csr[atomicAdd(&lcur[d.y - lo], 1)] = s.y;
        if (d.z >= lo && d.z < hi) csr[atomicAdd(&lcur[d.z - lo], 1)] = s.z;
        if (d.w >= lo && d.w < hi) csr[atomicAdd(&lcur[d.w - lo], 1)] = s.w;
    }
    int rem0 = e0 + ((e1 - e0) & ~3);
    for (int e = rem0 + tid; e < e1; e += 512) {
        int d = dst[e];
        if (d >= lo && d < hi) csr[atomicAdd(&lcur[d - lo], 1)] = src[e];
    }
}

// ---------------- gather2w: 2 nodes/wave, 16B/lane loads, champion structure -----
// R13-champion loop shape (s[8]/v[8] static unroll — proven spill-free) but each
// load is half8 (16B/lane): one instruction covers 4 rows (2 edges x 2 nodes),
// so the 8-deep batch holds 8KB/wave in flight (2x champion) at the same queue
// depth and ~same register count. Lane groups: g=lane>>4; {0,1}=node A parity
// {0,1}; {2,3}=node B. fl=lane&15 covers features fl*8..fl*8+7.
__device__ __forceinline__ void gather2w(
    const half8* __restrict__ hs8, const int* __restrict__ csr,
    const int* __restrict__ rowptr, int nA, int n,
    int g, int fl, int lane, floatx4& ac0, floatx4& ac1)
{
    const int ep  = g & 1;        // edge parity
    const int isB = g >> 1;       // which node this lane group serves
    const int nB  = nA + 1;

    int baseA = 0, cntA = 0, baseB = 0, cntB = 0;
    if (nA < n) {
        baseA = rowptr[nA];
        int mid = rowptr[nA + 1];
        cntA = mid - baseA;
        if (nB < n) { baseB = mid; cntB = rowptr[nB + 1] - mid; }
    }
    const int ccA = min(cntA, 64), ccB = min(cntB, 64);

    int idxA = (lane < ccA) ? __builtin_nontemporal_load(&csr[baseA + lane]) : 0;
    int idxB = (lane < ccB) ? __builtin_nontemporal_load(&csr[baseB + lane]) : 0;

    // self-loops (parity-0 groups only; each group adds its own node's row)
    if (ep == 0) {
        int nd = isB ? nB : nA;
        if (nd < n) {
            half8 s = hs8[(size_t)nd * 16 + fl];
            ac0[0] += (float)s[0]; ac0[1] += (float)s[1];
            ac0[2] += (float)s[2]; ac0[3] += (float)s[3];
            ac1[0] += (float)s[4]; ac1[1] += (float)s[5];
            ac1[2] += (float)s[6]; ac1[3] += (float)s[7];
        }
    }

    const int myc  = isB ? ccB : ccA;
    const int maxc = max(ccA, ccB);
    for (int j = 0; j < maxc; j += 16) {   // 16 edges/node per batch, 8 loads deep
        int s[8];
        half8 v[8];
        #pragma unroll
        for (int t = 0; t < 8; t++) {
            int e = j + 2 * t + ep;
            int eA = min(e, ccA - 1); eA = (eA < 0) ? 0 : eA;
            int eB = min(e, ccB - 1); eB = (eB < 0) ? 0 : eB;
            int sa = __shfl(idxA, eA, 64);
            int sb = __shfl(idxB, eB, 64);
            s[t] = isB ? sb : sa;
        }
        #pragma unroll
        for (int t = 0; t < 8; t++)
            v[t] = hs8[(size_t)s[t] * 16 + fl];
        #pragma unroll
        for (int t = 0; t < 8; t++) {
            if (j + 2 * t + ep < myc) {
                ac0[0] += (float)v[t][0]; ac0[1] += (float)v[t][1];
                ac0[2] += (float)v[t][2]; ac0[3] += (float)v[t][3];
                ac1[0] += (float)v[t][4]; ac1[1] += (float)v[t][5];
                ac1[2] += (float)v[t][6]; ac1[3] += (float)v[t][7];
            }
        }
    }

    // tails (cnt>64: ~never at Poisson(16)) — same body, idx reloaded per chunk
    const int cmax = max(cntA, cntB);
    for (int off = 64; off < cmax; off += 64) {
        int cA2 = cntA - off; cA2 = (cA2 < 0) ? 0 : min(cA2, 64);
        int cB2 = cntB - off; cB2 = (cB2 < 0) ? 0 : min(cB2, 64);
        int iA2 = (lane < cA2) ? csr[baseA + off + lane] : 0;
        int iB2 = (lane < cB2) ? csr[baseB + off + lane] : 0;
        int myc2 = isB ? cB2 : cA2;
        int m2   = max(cA2, cB2);
        for (int j = 0; j < m2; j += 16) {
            int s[8];
            half8 v[8];
            #pragma unroll
            for (int t = 0; t < 8; t++) {
                int e = j + 2 * t + ep;
                int eA = min(e, cA2 - 1); eA = (eA < 0) ? 0 : eA;
                int eB = min(e, cB2 - 1); eB = (eB < 0) ? 0 : eB;
                int sa = __shfl(iA2, eA, 64);
                int sb = __shfl(iB2, eB, 64);
                s[t] = isB ? sb : sa;
            }
            #pragma unroll
            for (int t = 0; t < 8; t++)
                v[t] = hs8[(size_t)s[t] * 16 + fl];
            #pragma unroll
            for (int t = 0; t < 8; t++) {
                if (j + 2 * t + ep < myc2) {
                    ac0[0] += (float)v[t][0]; ac0[1] += (float)v[t][1];
                    ac0[2] += (float)v[t][2]; ac0[3] += (float)v[t][3];
                    ac1[0] += (float)v[t][4]; ac1[1] += (float)v[t][5];
                    ac1[2] += (float)v[t][6]; ac1[3] += (float)v[t][7];
                }
            }
        }
    }

    // combine parity halves: xor16 pairs g0<->g1 (node A) and g2<->g3 (node B)
    #pragma unroll
    for (int q = 0; q < 4; q++) {
        ac0[q] += __shfl_xor(ac0[q], 16, 64);
        ac1[q] += __shfl_xor(ac1[q], 16, 64);
    }
}

// ---------------- aggmm: fused agg(layer1) + gemm2; 512 thr, 16 nodes/block -----
__global__ __launch_bounds__(512) void aggmm_k(
    const __half* __restrict__ hs, const int* __restrict__ rowptr,
    const int* __restrict__ csr, const float* __restrict__ dinv,
    const float* __restrict__ bias, const __half* __restrict__ WT,
    __half* __restrict__ Hout, int n)
{
    __shared__ __half alds[16][136];
    const int tid = threadIdx.x;
    const int wave = tid >> 6, lane = tid & 63;
    const int g = lane >> 4, fl = lane & 15;
    const int nb0 = blockIdx.x * 16;
    const int nA = nb0 + wave * 2;

    floatx4 ac0 = {0.f, 0.f, 0.f, 0.f}, ac1 = {0.f, 0.f, 0.f, 0.f};
    gather2w((const half8*)hs, csr, rowptr, nA, n, g, fl, lane, ac0, ac1);

    if ((g & 1) == 0) {   // groups 0 (node A) and 2 (node B) write
        int node = nA + (g >> 1);
        int row  = wave * 2 + (g >> 1);
        half8 hv;
        if (node < n) {
            float dv = dinv[node];
            const floatx4 bv0 = *(const floatx4*)&bias[fl * 8];
            const floatx4 bv1 = *(const floatx4*)&bias[fl * 8 + 4];
            hv[0] = (_Float16)fmaxf(dv * ac0[0] + bv0[0], 0.f);
            hv[1] = (_Float16)fmaxf(dv * ac0[1] + bv0[1], 0.f);
            hv[2] = (_Float16)fmaxf(dv * ac0[2] + bv0[2], 0.f);
            hv[3] = (_Float16)fmaxf(dv * ac0[3] + bv0[3], 0.f);
            hv[4] = (_Float16)fmaxf(dv * ac1[0] + bv1[0], 0.f);
            hv[5] = (_Float16)fmaxf(dv * ac1[1] + bv1[1], 0.f);
            hv[6] = (_Float16)fmaxf(dv * ac1[2] + bv1[2], 0.f);
            hv[7] = (_Float16)fmaxf(dv * ac1[3] + bv1[3], 0.f);
        } else {
            #pragma unroll
            for (int i = 0; i < 8; i++) hv[i] = (_Float16)0.f;
        }
        *(half8*)&alds[row][fl * 8] = hv;
    }
    __syncthreads();

    // 16x128 output tile: wave w owns col-tile ct = w (16 cols)
    const int quad = lane >> 4, l15 = lane & 15;
    const int ct = wave;
    half8 afr[4];
    #pragma unroll
    for (int kc = 0; kc < 4; kc++)
        afr[kc] = *(const half8*)&alds[l15][kc * 32 + quad * 8];

    floatx4 o0 = {0.f, 0.f, 0.f, 0.f};
    #pragma unroll
    for (int kc = 0; kc < 4; kc++) {
        half8 b = *(const half8*)(WT + (size_t)(ct * 16 + l15) * NF + kc * 32 + quad * 8);
        o0 = __builtin_amdgcn_mfma_f32_16x16x32_f16(afr[kc], b, o0, 0, 0, 0);
    }

    #pragma unroll
    for (int r = 0; r < 4; r++) {
        int node = nb0 + quad * 4 + r;
        if (node < n) {
            float s = dinv[node];
            Hout[(size_t)node * NF + ct * 16 + l15] = __float2half(o0[r] * s);
        }
    }
}

// ---------------- agg4: final aggregate (fp32 out); 256 thr, 8 nodes/block ------
__global__ __launch_bounds__(256) void agg4_k(
    const __half* __restrict__ hs, const int* __restrict__ rowptr,
    const int* __restrict__ csr, const float* __restrict__ dinv,
    const float* __restrict__ bias, float* __restrict__ outf, int n)
{
    const int tid = threadIdx.x;
    const int wave = tid >> 6, lane = tid & 63;
    const int g = lane >> 4, fl = lane & 15;
    const int nA = blockIdx.x * 8 + wave * 2;
    if (nA >= n) return;

    floatx4 ac0 = {0.f, 0.f, 0.f, 0.f}, ac1 = {0.f, 0.f, 0.f, 0.f};
    gather2w((const half8*)hs, csr, rowptr, nA, n, g, fl, lane, ac0, ac1);

    if ((g & 1) == 0) {
        int node = nA + (g >> 1);
        if (node < n) {
            float dv = dinv[node];
            const floatx4 bv0 = *(const floatx4*)&bias[fl * 8];
            const floatx4 bv1 = *(const floatx4*)&bias[fl * 8 + 4];
            floatx4 w0, w1;
            w0[0] = dv * ac0[0] + bv0[0]; w0[1] = dv * ac0[1] + bv0[1];
            w0[2] = dv * ac0[2] + bv0[2]; w0[3] = dv * ac0[3] + bv0[3];
            w1[0] = dv * ac1[0] + bv1[0]; w1[1] = dv * ac1[1] + bv1[1];
            w1[2] = dv * ac1[2] + bv1[2]; w1[3] = dv * ac1[3] + bv1[3];
            *(floatx4*)(outf + (size_t)node * NF + fl * 8)     = w0;
            *(floatx4*)(outf + (size_t)node * NF + fl * 8 + 4) = w1;
        }
    }
}

// ---------------- launch ----------------

extern "C" void kernel_launch(void* const* d_in, const int* in_sizes, int n_in,
                              void* d_out, int out_size, void* d_ws, size_t ws_size,
                              hipStream_t stream) {
    const float* x  = (const float*)d_in[0];
    const int*   ei = (const int*)d_in[1];
    const float* W1 = (const float*)d_in[2];
    const float* b1 = (const float*)d_in[3];
    const float* W2 = (const float*)d_in[4];
    const float* b2 = (const float*)d_in[5];
    float* out = (float*)d_out;

    const int N = in_sizes[0] / NF;   // 50000
    const int E = in_sizes[1] / 2;    // 800000
    const int* src = ei;
    const int* dst = ei + E;

    char* ws = (char*)d_ws;
    size_t off = 0;
    auto alloc = [&](size_t bytes) {
        void* p = ws + off;
        off += bytes;
        off = (off + 63) & ~(size_t)63;
        return p;
    };
    unsigned char* pcnt = (unsigned char*)alloc((size_t)KC * N);  // counts->coff
    int*    rowptr  = (int*)alloc((size_t)(N + 1) * 4);   // local prefixes
    int*    rowptr2 = (int*)alloc((size_t)(N + 1) * 4);   // corrected (agg uses)
    int*    csr     = (int*)alloc((size_t)E * 4);
    float*  dinv    = (float*)alloc((size_t)N * 4);
    int*    bsum    = (int*)alloc((size_t)256 * 4);
    __half* WT1     = (__half*)alloc((size_t)NF * NF * 2);
    __half* WT2     = (__half*)alloc((size_t)NF * NF * 2);
    __half* H16     = (__half*)alloc((size_t)N * NF * 2);
    __half* A16     = (__half*)alloc((size_t)N * NF * 2);

    int nb  = (N + 255) / 256;                 // 196 (<=256)
    int Ec  = (((E + KC - 1) / KC) + 3) & ~3;  // chunk size, multiple of 4
    int GB2 = (N + 127) / 128;                 // gemm1 blocks (512 thr)
    int fb  = (N + 15) / 16;                   // aggmm blocks (16 nodes, 512 thr)
    int ab  = (N + 7) / 8;                     // agg4 blocks (8 nodes, 256 thr)

    count2_k<<<KC * NPART, 512, 0, stream>>>(dst, pcnt, E, N, Ec);
    pscan2_k<<<nb + 128, 256, 0, stream>>>(pcnt, dinv, rowptr, bsum, N, N, nb,
                                           W1, W2, WT1, WT2);
    mid_k<<<GB2 + KC * NPART, 512, 0, stream>>>(src, dst, rowptr, pcnt, bsum,
                                                rowptr2, csr, E, N, Ec, nb,
                                                x, WT1, dinv, H16, GB2);
    // fused layer-1 aggregate + layer-2 GEMM (2-node/wave 16B-load gather)
    aggmm_k<<<fb, 512, 0, stream>>>(H16, rowptr2, csr, dinv, b1, WT2, A16, N);
    // final aggregate -> fp32 output
    agg4_k<<<ab, 256, 0, stream>>>(A16, rowptr2, csr, dinv, b2, out, N);
}